// Round 5
// baseline (232.037 us; speedup 1.0000x reference)
//
#include <hip/hip_runtime.h>

#define SEQ 2048
#define DM  1024
#define NH  16
#define DK  64
#define BATCH 2
#define MROWS (BATCH * SEQ)
#define PPITCH 72   // P-tile LDS pitch (shorts) — round-0 verified

typedef __attribute__((ext_vector_type(8))) short bf16x8;   // 8 bf16 = 4 VGPRs
typedef __attribute__((ext_vector_type(4))) float f32x4;    // MFMA C/D

extern "C" __device__ float __ocml_native_exp2_f32(float);  // single v_exp_f32

__device__ __forceinline__ float bf2f(unsigned short u) {
    union { unsigned int i; float f; } v;
    v.i = ((unsigned int)u) << 16;
    return v.f;
}

__device__ __forceinline__ unsigned short f2bf(float f) {
    union { float f; unsigned int i; } v;
    v.f = f;
    unsigned int r = v.i + 0x7FFFu + ((v.i >> 16) & 1u);  // RNE
    return (unsigned short)(r >> 16);
}

// pack two f32 -> two bf16 (truncation) in ONE VALU op.
// perm sel 0x07060302 with s0=b,s1=a: D = {lo: a.hi16, hi: b.hi16}
__device__ __forceinline__ unsigned int pk_trunc(float a, float b) {
    return __builtin_amdgcn_perm(__float_as_uint(b), __float_as_uint(a),
                                 0x07060302u);
}

__device__ __forceinline__ uint4 pack8(float4 x, float4 y) {
    uint4 r;
    r.x = (unsigned)f2bf(x.x) | ((unsigned)f2bf(x.y) << 16);
    r.y = (unsigned)f2bf(x.z) | ((unsigned)f2bf(x.w) << 16);
    r.z = (unsigned)f2bf(y.x) | ((unsigned)f2bf(y.y) << 16);
    r.w = (unsigned)f2bf(y.z) | ((unsigned)f2bf(y.w) << 16);
    return r;
}

// async global->LDS DMA, 16 B per lane; LDS dest = wave-uniform base + lane*16.
__device__ __forceinline__ void gll16(const void* g, void* l) {
    __builtin_amdgcn_global_load_lds(
        (const __attribute__((address_space(1))) unsigned int*)g,
        (__attribute__((address_space(3))) unsigned int*)l, 16, 0, 0);
}

// Runtime storage-dtype probe (bf16 vs fp32 dataset storage). flag: 0=bf16, 1=fp32.
__global__ void detect_dtype(const unsigned short* __restrict__ q,
                             unsigned int* __restrict__ flag) {
    const int lane = threadIdx.x;
    unsigned short u = q[lane * 2];
    int e = (u >> 7) & 0xFF;
    int hit = (e >= 100 && e <= 135) ? 1 : 0;
    unsigned long long m = __ballot(hit);
    if (lane == 0) *flag = (__popcll(m) >= 48) ? 0u : 1u;
}

// ---- one-time dtype normalization: all 11 tensors -> bf16 workspace ----
// Regions 3 (Wq) and 7 (bq) are scaled by (1/8)*log2(e): the Q projection
// emerges pre-scaled so attention scores are already in log2 domain and
// softmax uses a bare v_exp_f32 (exp2).
#define QSCALE 0.1803368801111204f   // 0.125 * log2(e)
#define CVT_TOTAL 16781312u
struct CvtArgs {
    const void* src[11];
    unsigned short* dst[11];
};

__global__ __launch_bounds__(256) void convert_all(CvtArgs a,
                                                   const unsigned int* __restrict__ flagp) {
    const unsigned int f = *flagp;
    const size_t e0 = ((size_t)blockIdx.x * 256 + threadIdx.x) * 8;
    if (e0 >= CVT_TOTAL) return;
    const unsigned int cum[12] = {0u, 4194304u, 8388608u, 12582912u, 13631488u,
                                  14680064u, 15728640u, 16777216u, 16778240u,
                                  16779264u, 16780288u, 16781312u};
    int r = 0;
    #pragma unroll
    for (int i = 1; i < 11; ++i) r += (e0 >= cum[i]) ? 1 : 0;
    const size_t local = e0 - cum[r];
    const float sc = (r == 3 || r == 7) ? QSCALE : 1.0f;
    if (f) {
        const float* s = (const float*)a.src[r] + local;
        float4 x = *(const float4*)s;
        float4 y = *(const float4*)(s + 4);
        x.x *= sc; x.y *= sc; x.z *= sc; x.w *= sc;
        y.x *= sc; y.y *= sc; y.z *= sc; y.w *= sc;
        *(uint4*)(a.dst[r] + local) = pack8(x, y);
    } else {
        const unsigned short* s = (const unsigned short*)a.src[r] + local;
        if (sc != 1.0f) {
            unsigned short o[8];
            #pragma unroll
            for (int i = 0; i < 8; ++i) o[i] = f2bf(bf2f(s[i]) * sc);
            *(uint4*)(a.dst[r] + local) = *(const uint4*)o;
        } else {
            *(uint4*)(a.dst[r] + local) = *(const uint4*)s;
        }
    }
}

// ---- MFMA GEMM core (byte-identical to round 8 — isolates attn deltas) ----
__device__ __forceinline__ void gemm_core(
    const unsigned short* __restrict__ A, const unsigned short* __restrict__ W,
    const unsigned short* __restrict__ bias, void* __restrict__ C, int cMode)
{
    __shared__ unsigned short Al[64 * 64];    //  8 KB
    __shared__ unsigned short Bl[128 * 64];   // 16 KB

    const int tid  = threadIdx.x;
    const int w    = tid >> 6;
    const int lane = tid & 63;
    const int lo   = lane & 15;
    const int quad = lane >> 4;
    const int bm   = blockIdx.y * 64;
    const int bn   = blockIdx.x * 128;

    const int r8  = lane >> 3;
    const int csw = ((lane ^ r8) & 7) * 8;   // swizzled chunk (shorts)
    const unsigned short* gA = A + (size_t)(bm + w * 16 + r8) * DM + csw;
    const unsigned short* gB = W + (size_t)(bn + w * 32 + r8) * DM + csw;
    unsigned short* lA = &Al[(w * 16) * 64];
    unsigned short* lB = &Bl[(w * 32) * 64];

    f32x4 acc[4][2];
    #pragma unroll
    for (int i = 0; i < 4; ++i)
        #pragma unroll
        for (int n = 0; n < 2; ++n) acc[i][n] = (f32x4){0.f, 0.f, 0.f, 0.f};

    const int swz = (lo & 7);

    for (int k0 = 0; k0 < DM; k0 += 64) {
        __syncthreads();
        #pragma unroll
        for (int j = 0; j < 2; ++j)
            gll16(gA + (size_t)j * 8 * DM + k0, lA + j * 8 * 64);
        #pragma unroll
        for (int j = 0; j < 4; ++j)
            gll16(gB + (size_t)j * 8 * DM + k0, lB + j * 8 * 64);
        __syncthreads();

        #pragma unroll
        for (int kc = 0; kc < 2; ++kc) {
            bf16x8 af[4], bfr[2];
            #pragma unroll
            for (int i = 0; i < 4; ++i)
                af[i] = *(const bf16x8*)&Al[(i * 16 + lo) * 64 +
                                            (((kc * 4 + quad) ^ swz) * 8)];
            #pragma unroll
            for (int n = 0; n < 2; ++n)
                bfr[n] = *(const bf16x8*)&Bl[(w * 32 + n * 16 + lo) * 64 +
                                             (((kc * 4 + quad) ^ swz) * 8)];
            #pragma unroll
            for (int i = 0; i < 4; ++i)
                #pragma unroll
                for (int n = 0; n < 2; ++n)
                    acc[i][n] = __builtin_amdgcn_mfma_f32_16x16x32_bf16(af[i], bfr[n], acc[i][n], 0, 0, 0);
        }
    }

    float bj[2];
    #pragma unroll
    for (int n = 0; n < 2; ++n)
        bj[n] = bf2f(bias[bn + w * 32 + n * 16 + lo]);

    if (cMode == 2) {
        #pragma unroll
        for (int i = 0; i < 4; ++i)
            #pragma unroll
            for (int n = 0; n < 2; ++n) {
                const int row0 = bm + i * 16 + quad * 4;
                const int col  = bn + w * 32 + n * 16 + lo;
                ushort4 cv;
                cv.x = f2bf(acc[i][n][0] + bj[n]);
                cv.y = f2bf(acc[i][n][1] + bj[n]);
                cv.z = f2bf(acc[i][n][2] + bj[n]);
                cv.w = f2bf(acc[i][n][3] + bj[n]);
                const size_t off = ((size_t)((row0 >> 11) * 16 + (col >> 6)) * 64
                                    + (col & 63)) * 2048 + (row0 & 2047);
                *(ushort4*)((unsigned short*)C + off) = cv;
            }
    } else {
        #pragma unroll
        for (int i = 0; i < 4; ++i)
            #pragma unroll
            for (int n = 0; n < 2; ++n)
                #pragma unroll
                for (int r = 0; r < 4; ++r) {
                    const int row = bm + i * 16 + quad * 4 + r;
                    const size_t off = (size_t)row * DM + bn + w * 32 + n * 16 + lo;
                    const float vv = acc[i][n][r] + bj[n];
                    if (cMode == 1) ((float*)C)[off] = vv;
                    else            ((unsigned short*)C)[off] = f2bf(vv);
                }
    }
}

__global__ __launch_bounds__(256, 4) void gemm_qkv(
    const unsigned short* __restrict__ qa, const unsigned short* __restrict__ ka,
    const unsigned short* __restrict__ va,
    const unsigned short* __restrict__ wq, const unsigned short* __restrict__ wk,
    const unsigned short* __restrict__ wv,
    const unsigned short* __restrict__ bq, const unsigned short* __restrict__ bk,
    const unsigned short* __restrict__ bv,
    unsigned short* __restrict__ oq, unsigned short* __restrict__ ok,
    unsigned short* __restrict__ ovT)
{
    if (blockIdx.z == 0)      gemm_core(qa, wq, bq, oq, 0);
    else if (blockIdx.z == 1) gemm_core(ka, wk, bk, ok, 0);
    else                      gemm_core(va, wv, bv, ovT, 2);   // V -> [bh][d][s]
}

__global__ __launch_bounds__(256, 4) void gemm_out(
    const unsigned short* __restrict__ A, const unsigned short* __restrict__ W,
    const unsigned short* __restrict__ B, void* __restrict__ C,
    const unsigned int* __restrict__ flagp)
{
    gemm_core(A, W, B, C, (int)*flagp);
}

// ---- MFMA flash attention v8: 3-buffer depth-2 pipeline, counted vmcnt ----
// v7 (57.6 us) showed the residual is still stall: 4,320 cy/tile wall vs
// ~2,100 cy of per-SIMD work. Cause: __syncthreads' implicit vmcnt(0) drain
// waits for the JUST-issued t+1 loads too — prefetch depth is capped <1
// tile. Fix (T4): 3 LDS buffers, stage t+2 at top of tile t, and end each
// tile with inline-asm `s_waitcnt vmcnt(4)` (t+1's 4 oldest loads retired;
// t+2's 4 stay in flight) + raw s_barrier + sched_barrier(0). Tail tiles
// drain vmcnt(0). Safety: buffer (t+2)%3 was last read in tile t-1, whose
// ds_reads completed before the end-of-(t-1) barrier (consumed by MFMAs
// under lgkmcnt); the overwrite is issued after that barrier. Numerics
// byte-identical to the verified round-0 kernel.
__global__ __launch_bounds__(256) void attn_mfma6(
    const unsigned short* __restrict__ Q,    // pre-scaled (log2 domain)
    const unsigned short* __restrict__ K,
    const unsigned short* __restrict__ VT,   // [bh][64][2048]
    unsigned short* __restrict__ CTX)
{
    __shared__ unsigned short Kl[3][64 * 64];     // 24 KB  [key][d] swizzled
    __shared__ unsigned short Vl[3][64 * 64];     // 24 KB  [d][key] swizzled
    __shared__ unsigned short Pl[4][2][16 * PPITCH];  // 18.4 KB

    const int tid  = threadIdx.x;
    const int w    = tid >> 6;
    const int lane = tid & 63;
    const int lo   = lane & 15;
    const int quad = lane >> 4;
    const int bh = blockIdx.y;
    const int b  = bh >> 4;
    const int h  = bh & 15;
    const int q0 = blockIdx.x * 128 + w * 32;

    bf16x8 aq[2][2];
    #pragma unroll
    for (int f = 0; f < 2; ++f)
        #pragma unroll
        for (int c = 0; c < 2; ++c)
            aq[f][c] = *(const bf16x8*)(Q + (size_t)(b * SEQ + q0 + f * 16 + lo) * DM
                                        + h * 64 + c * 32 + quad * 8);

    f32x4 o[2][4];
    #pragma unroll
    for (int f = 0; f < 2; ++f)
        #pragma unroll
        for (int dt = 0; dt < 4; ++dt) o[f][dt] = (f32x4){0.f, 0.f, 0.f, 0.f};
    f32x4 lacc[2];
    lacc[0] = (f32x4){0.f, 0.f, 0.f, 0.f};
    lacc[1] = (f32x4){0.f, 0.f, 0.f, 0.f};

    const short one_s = (short)0x3F80;   // bf16 1.0
    const bf16x8 ones = {one_s, one_s, one_s, one_s, one_s, one_s, one_s, one_s};

    const int r8  = lane >> 3;
    const int csw = ((lane ^ r8) & 7) * 8;
    const int swz = lo & 7;
    const unsigned short* Kg = K + (size_t)b * SEQ * DM + h * 64;
    const unsigned short* Vg = VT + (size_t)bh * 64 * 2048;

    // per-wave stage of key-tile jt into buffer bb: 4 gll16 (2 K + 2 V)
    #define STAGE(jt, bb) do {                                              \
        const int _jn = (jt) * 64;                                          \
        _Pragma("unroll")                                                   \
        for (int _j = 0; _j < 2; ++_j) {                                    \
            gll16(Kg + (size_t)(_jn + w * 16 + _j * 8 + r8) * DM + csw,     \
                  &Kl[bb][(w * 16 + _j * 8) * 64]);                         \
            gll16(Vg + (size_t)(w * 16 + _j * 8 + r8) * 2048 + _jn + csw,   \
                  &Vl[bb][(w * 16 + _j * 8) * 64]);                         \
        }                                                                   \
    } while (0)

    // prologue: stage tiles 0 and 1; wait for tile 0 only (vmcnt(4))
    STAGE(0, 0);
    STAGE(1, 1);
    asm volatile("s_waitcnt vmcnt(4)" ::: "memory");
    __builtin_amdgcn_s_barrier();
    __builtin_amdgcn_sched_barrier(0);

    const int NT = SEQ / 64;
    int cur = 0;
    for (int t = 0; t < NT; ++t) {
        // issue tile t+2's staging FIRST — two tiles of compute to hide under
        if (t + 2 < NT) {
            const int nb = (cur + 2 >= 3) ? cur - 1 : cur + 2;
            STAGE(t + 2, nb);
        }

        const unsigned short* Kc = Kl[cur];
        const unsigned short* Vc = Vl[cur];

        // S^T: rows = keys, cols = queries (already log2-scaled)
        f32x4 st[4][2];
        __builtin_amdgcn_s_setprio(1);
        #pragma unroll
        for (int kt = 0; kt < 4; ++kt) {
            bf16x8 ak0 = *(const bf16x8*)&Kc[(kt * 16 + lo) * 64 + ((quad ^ swz) * 8)];
            bf16x8 ak1 = *(const bf16x8*)&Kc[(kt * 16 + lo) * 64 + (((4 + quad) ^ swz) * 8)];
            #pragma unroll
            for (int f = 0; f < 2; ++f) {
                f32x4 c = (f32x4){0.f, 0.f, 0.f, 0.f};
                c = __builtin_amdgcn_mfma_f32_16x16x32_bf16(ak0, aq[f][0], c, 0, 0, 0);
                c = __builtin_amdgcn_mfma_f32_16x16x32_bf16(ak1, aq[f][1], c, 0, 0, 0);
                st[kt][f] = c;
            }
        }
        __builtin_amdgcn_s_setprio(0);

        // p = exp2(s); packed trunc P^T round-trip
        #pragma unroll
        for (int f = 0; f < 2; ++f)
            #pragma unroll
            for (int kt = 0; kt < 4; ++kt) {
                float p0 = __ocml_native_exp2_f32(st[kt][f][0]);
                float p1 = __ocml_native_exp2_f32(st[kt][f][1]);
                float p2 = __ocml_native_exp2_f32(st[kt][f][2]);
                float p3 = __ocml_native_exp2_f32(st[kt][f][3]);
                uint2 pv;
                pv.x = pk_trunc(p0, p1);
                pv.y = pk_trunc(p2, p3);
                *(uint2*)&Pl[w][f][lo * PPITCH + kt * 16 + quad * 4] = pv;
            }
        // same-wave write->read ordering via lgkmcnt
        bf16x8 ap[2][2];
        #pragma unroll
        for (int f = 0; f < 2; ++f)
            #pragma unroll
            for (int c = 0; c < 2; ++c)
                ap[f][c] = *(const bf16x8*)&Pl[w][f][lo * PPITCH + c * 32 + quad * 8];

        __builtin_amdgcn_s_setprio(1);
        // lsum via ones-MFMA: C[q][*] = sum_k P[q,k], rows match O layout
        #pragma unroll
        for (int f = 0; f < 2; ++f) {
            lacc[f] = __builtin_amdgcn_mfma_f32_16x16x32_bf16(ap[f][0], ones, lacc[f], 0, 0, 0);
            lacc[f] = __builtin_amdgcn_mfma_f32_16x16x32_bf16(ap[f][1], ones, lacc[f], 0, 0, 0);
        }

        #pragma unroll
        for (int dt = 0; dt < 4; ++dt) {
            bf16x8 bv0 = *(const bf16x8*)&Vc[(dt * 16 + lo) * 64 + ((quad ^ swz) * 8)];
            bf16x8 bv1 = *(const bf16x8*)&Vc[(dt * 16 + lo) * 64 + (((4 + quad) ^ swz) * 8)];
            #pragma unroll
            for (int f = 0; f < 2; ++f) {
                o[f][dt] = __builtin_amdgcn_mfma_f32_16x16x32_bf16(ap[f][0], bv0, o[f][dt], 0, 0, 0);
                o[f][dt] = __builtin_amdgcn_mfma_f32_16x16x32_bf16(ap[f][1], bv1, o[f][dt], 0, 0, 0);
            }
        }
        __builtin_amdgcn_s_setprio(0);

        // end of tile: t+1's 4 oldest loads must retire; t+2's 4 stay in
        // flight (counted vmcnt — never 0 in steady state). Tail drains.
        if (t + 2 < NT) {
            asm volatile("s_waitcnt vmcnt(4)" ::: "memory");
        } else {
            asm volatile("s_waitcnt vmcnt(0)" ::: "memory");
        }
        __builtin_amdgcn_s_barrier();
        __builtin_amdgcn_sched_barrier(0);

        cur = (cur == 2) ? 0 : cur + 1;
    }
    #undef STAGE

    // epilogue: l for row q=quad*4+r is lacc[f][r] in-lane — no shuffles
    #pragma unroll
    for (int f = 0; f < 2; ++f)
        #pragma unroll
        for (int r = 0; r < 4; ++r) {
            const float inv = 1.0f / lacc[f][r];
            const size_t base = (size_t)(b * SEQ + q0 + f * 16 + quad * 4 + r) * DM
                                + h * 64 + lo;
            #pragma unroll
            for (int dt = 0; dt < 4; ++dt)
                CTX[base + dt * 16] = f2bf(o[f][dt][r] * inv);
        }
}

extern "C" void kernel_launch(void* const* d_in, const int* in_sizes, int n_in,
                              void* d_out, int out_size, void* d_ws, size_t ws_size,
                              hipStream_t stream) {
    const size_t E4 = 4194304, E1 = 1048576;
    unsigned short* qb  = (unsigned short*)d_ws;
    unsigned short* kb  = qb  + E4;
    unsigned short* vb  = kb  + E4;
    unsigned short* wqb = vb  + E4;
    unsigned short* wkb = wqb + E1;
    unsigned short* wvb = wkb + E1;
    unsigned short* wob = wvb + E1;
    unsigned short* bqb = wob + E1;
    unsigned short* bkb = bqb + 1024;
    unsigned short* bvb = bkb + 1024;
    unsigned short* bob = bvb + 1024;
    unsigned short* wsQ = bob + 1024;
    unsigned short* wsK = wsQ + E4;
    unsigned short* wsVt = wsK + E4;   // V projection, [bh][64][2048]
    unsigned int*  flag = (unsigned int*)(wsVt + E4);
    unsigned short* wsC = qb;   // alias: qb dead after the QKV GEMM dispatch

    detect_dtype<<<1, 64, 0, stream>>>((const unsigned short*)d_in[0], flag);

    CvtArgs ca;
    ca.src[0] = d_in[0];  ca.dst[0] = qb;
    ca.src[1] = d_in[1];  ca.dst[1] = kb;
    ca.src[2] = d_in[2];  ca.dst[2] = vb;
    ca.src[3] = d_in[3];  ca.dst[3] = wqb;   // scaled 0.125*log2e
    ca.src[4] = d_in[5];  ca.dst[4] = wkb;
    ca.src[5] = d_in[7];  ca.dst[5] = wvb;
    ca.src[6] = d_in[9];  ca.dst[6] = wob;
    ca.src[7] = d_in[4];  ca.dst[7] = bqb;   // scaled 0.125*log2e
    ca.src[8] = d_in[6];  ca.dst[8] = bkb;
    ca.src[9] = d_in[8];  ca.dst[9] = bvb;
    ca.src[10] = d_in[10]; ca.dst[10] = bob;
    convert_all<<<(CVT_TOTAL / 8 + 255) / 256, 256, 0, stream>>>(ca, flag);

    dim3 gq(DM / 128, MROWS / 64, 3);    // (8, 64, 3) = 1536 blocks
    gemm_qkv<<<gq, 256, 0, stream>>>(qb, kb, vb, wqb, wkb, wvb,
                                     bqb, bkb, bvb, wsQ, wsK, wsVt);

    dim3 ga(SEQ / 128, BATCH * NH);      // (16, 32)
    attn_mfma6<<<ga, 256, 0, stream>>>(wsQ, wsK, wsVt, wsC);

    dim3 go(DM / 128, MROWS / 64);       // (8, 64) = 512 blocks
    gemm_out<<<go, 256, 0, stream>>>(wsC, wob, bob, d_out, flag);
}

// Round 6
// 223.606 us; speedup vs baseline: 1.0377x; 1.0377x over previous
//
#include <hip/hip_runtime.h>

#define SEQ 2048
#define DM  1024
#define NH  16
#define DK  64
#define BATCH 2
#define MROWS (BATCH * SEQ)
#define PPITCH 72   // P-tile LDS pitch (shorts) — round-0 verified

typedef __attribute__((ext_vector_type(8))) short bf16x8;   // 8 bf16 = 4 VGPRs
typedef __attribute__((ext_vector_type(4))) float f32x4;    // MFMA C/D

extern "C" __device__ float __ocml_native_exp2_f32(float);  // single v_exp_f32

__device__ __forceinline__ float bf2f(unsigned short u) {
    union { unsigned int i; float f; } v;
    v.i = ((unsigned int)u) << 16;
    return v.f;
}

__device__ __forceinline__ unsigned short f2bf(float f) {
    union { float f; unsigned int i; } v;
    v.f = f;
    unsigned int r = v.i + 0x7FFFu + ((v.i >> 16) & 1u);  // RNE
    return (unsigned short)(r >> 16);
}

// pack two f32 -> two bf16 (truncation) in ONE VALU op.
// perm sel 0x07060302 with s0=b,s1=a: D = {lo: a.hi16, hi: b.hi16}
__device__ __forceinline__ unsigned int pk_trunc(float a, float b) {
    return __builtin_amdgcn_perm(__float_as_uint(b), __float_as_uint(a),
                                 0x07060302u);
}

__device__ __forceinline__ uint4 pack8(float4 x, float4 y) {
    uint4 r;
    r.x = (unsigned)f2bf(x.x) | ((unsigned)f2bf(x.y) << 16);
    r.y = (unsigned)f2bf(x.z) | ((unsigned)f2bf(x.w) << 16);
    r.z = (unsigned)f2bf(y.x) | ((unsigned)f2bf(y.y) << 16);
    r.w = (unsigned)f2bf(y.z) | ((unsigned)f2bf(y.w) << 16);
    return r;
}

// async global->LDS DMA, 16 B per lane; LDS dest = wave-uniform base + lane*16.
__device__ __forceinline__ void gll16(const void* g, void* l) {
    __builtin_amdgcn_global_load_lds(
        (const __attribute__((address_space(1))) unsigned int*)g,
        (__attribute__((address_space(3))) unsigned int*)l, 16, 0, 0);
}

// Runtime storage-dtype probe (bf16 vs fp32 dataset storage). flag: 0=bf16, 1=fp32.
__global__ void detect_dtype(const unsigned short* __restrict__ q,
                             unsigned int* __restrict__ flag) {
    const int lane = threadIdx.x;
    unsigned short u = q[lane * 2];
    int e = (u >> 7) & 0xFF;
    int hit = (e >= 100 && e <= 135) ? 1 : 0;
    unsigned long long m = __ballot(hit);
    if (lane == 0) *flag = (__popcll(m) >= 48) ? 0u : 1u;
}

// ---- one-time dtype normalization: all 11 tensors -> bf16 workspace ----
// Regions 3 (Wq) and 7 (bq) are scaled by (1/8)*log2(e): the Q projection
// emerges pre-scaled so attention scores are already in log2 domain and
// softmax uses a bare v_exp_f32 (exp2).
#define QSCALE 0.1803368801111204f   // 0.125 * log2(e)
#define CVT_TOTAL 16781312u
struct CvtArgs {
    const void* src[11];
    unsigned short* dst[11];
};

__global__ __launch_bounds__(256) void convert_all(CvtArgs a,
                                                   const unsigned int* __restrict__ flagp) {
    const unsigned int f = *flagp;
    const size_t e0 = ((size_t)blockIdx.x * 256 + threadIdx.x) * 8;
    if (e0 >= CVT_TOTAL) return;
    const unsigned int cum[12] = {0u, 4194304u, 8388608u, 12582912u, 13631488u,
                                  14680064u, 15728640u, 16777216u, 16778240u,
                                  16779264u, 16780288u, 16781312u};
    int r = 0;
    #pragma unroll
    for (int i = 1; i < 11; ++i) r += (e0 >= cum[i]) ? 1 : 0;
    const size_t local = e0 - cum[r];
    const float sc = (r == 3 || r == 7) ? QSCALE : 1.0f;
    if (f) {
        const float* s = (const float*)a.src[r] + local;
        float4 x = *(const float4*)s;
        float4 y = *(const float4*)(s + 4);
        x.x *= sc; x.y *= sc; x.z *= sc; x.w *= sc;
        y.x *= sc; y.y *= sc; y.z *= sc; y.w *= sc;
        *(uint4*)(a.dst[r] + local) = pack8(x, y);
    } else {
        const unsigned short* s = (const unsigned short*)a.src[r] + local;
        if (sc != 1.0f) {
            unsigned short o[8];
            #pragma unroll
            for (int i = 0; i < 8; ++i) o[i] = f2bf(bf2f(s[i]) * sc);
            *(uint4*)(a.dst[r] + local) = *(const uint4*)o;
        } else {
            *(uint4*)(a.dst[r] + local) = *(const uint4*)s;
        }
    }
}

// ---- MFMA GEMM core v2: 128x128 tile (m93->m97 ladder step) ----
// Old core: 64x128 block = 24 KB staged per 64 block-MFMAs (ratio 2.7:1),
// implied ~250-340 TF across the 4 GEMMs (~140 us of the 232 us total).
// New: 128x128 block, 4 waves in 2x2 quadrants, each wave acc[4][4] (64x64),
// 32 KB staged per 128 block-MFMAs (ratio 4:1) — the documented 517->874 TF
// step. Swizzle algebra is byte-identical to the verified core: both the
// staging chunk ((lane^r8)&7) and read chunk ((kc*4+quad)^(lo&7)) depend
// only on row mod 8, which is unchanged by the wr*64 / w*32 row offsets.
__device__ __forceinline__ void gemm_core(
    const unsigned short* __restrict__ A, const unsigned short* __restrict__ W,
    const unsigned short* __restrict__ bias, void* __restrict__ C, int cMode)
{
    __shared__ unsigned short Al[128 * 64];   // 16 KB
    __shared__ unsigned short Bl[128 * 64];   // 16 KB

    const int tid  = threadIdx.x;
    const int w    = tid >> 6;
    const int lane = tid & 63;
    const int lo   = lane & 15;
    const int quad = lane >> 4;
    const int wr   = w >> 1;     // wave row-half (0..1)
    const int wc   = w & 1;      // wave col-half (0..1)
    const int bm   = blockIdx.y * 128;
    const int bn   = blockIdx.x * 128;

    const int r8  = lane >> 3;
    const int csw = ((lane ^ r8) & 7) * 8;   // swizzled chunk (shorts)
    // wave w stages A rows [w*32, w*32+32) and B rows [w*32, w*32+32)
    const unsigned short* gA = A + (size_t)(bm + w * 32 + r8) * DM + csw;
    const unsigned short* gB = W + (size_t)(bn + w * 32 + r8) * DM + csw;
    unsigned short* lA = &Al[(w * 32) * 64];
    unsigned short* lB = &Bl[(w * 32) * 64];

    f32x4 acc[4][4];
    #pragma unroll
    for (int i = 0; i < 4; ++i)
        #pragma unroll
        for (int n = 0; n < 4; ++n) acc[i][n] = (f32x4){0.f, 0.f, 0.f, 0.f};

    const int swz = (lo & 7);

    for (int k0 = 0; k0 < DM; k0 += 64) {
        __syncthreads();
        #pragma unroll
        for (int j = 0; j < 4; ++j) {
            gll16(gA + (size_t)j * 8 * DM + k0, lA + j * 8 * 64);
            gll16(gB + (size_t)j * 8 * DM + k0, lB + j * 8 * 64);
        }
        __syncthreads();

        #pragma unroll
        for (int kc = 0; kc < 2; ++kc) {
            bf16x8 af[4], bfr[4];
            #pragma unroll
            for (int i = 0; i < 4; ++i)
                af[i] = *(const bf16x8*)&Al[(wr * 64 + i * 16 + lo) * 64 +
                                            (((kc * 4 + quad) ^ swz) * 8)];
            #pragma unroll
            for (int n = 0; n < 4; ++n)
                bfr[n] = *(const bf16x8*)&Bl[(wc * 64 + n * 16 + lo) * 64 +
                                             (((kc * 4 + quad) ^ swz) * 8)];
            #pragma unroll
            for (int i = 0; i < 4; ++i)
                #pragma unroll
                for (int n = 0; n < 4; ++n)
                    acc[i][n] = __builtin_amdgcn_mfma_f32_16x16x32_bf16(af[i], bfr[n], acc[i][n], 0, 0, 0);
        }
    }

    float bj[4];
    #pragma unroll
    for (int n = 0; n < 4; ++n)
        bj[n] = bf2f(bias[bn + wc * 64 + n * 16 + lo]);

    if (cMode == 2) {
        #pragma unroll
        for (int i = 0; i < 4; ++i)
            #pragma unroll
            for (int n = 0; n < 4; ++n) {
                const int row0 = bm + wr * 64 + i * 16 + quad * 4;
                const int col  = bn + wc * 64 + n * 16 + lo;
                ushort4 cv;
                cv.x = f2bf(acc[i][n][0] + bj[n]);
                cv.y = f2bf(acc[i][n][1] + bj[n]);
                cv.z = f2bf(acc[i][n][2] + bj[n]);
                cv.w = f2bf(acc[i][n][3] + bj[n]);
                const size_t off = ((size_t)((row0 >> 11) * 16 + (col >> 6)) * 64
                                    + (col & 63)) * 2048 + (row0 & 2047);
                *(ushort4*)((unsigned short*)C + off) = cv;
            }
    } else {
        #pragma unroll
        for (int i = 0; i < 4; ++i)
            #pragma unroll
            for (int n = 0; n < 4; ++n)
                #pragma unroll
                for (int r = 0; r < 4; ++r) {
                    const int row = bm + wr * 64 + i * 16 + quad * 4 + r;
                    const size_t off = (size_t)row * DM + bn + wc * 64 + n * 16 + lo;
                    const float vv = acc[i][n][r] + bj[n];
                    if (cMode == 1) ((float*)C)[off] = vv;
                    else            ((unsigned short*)C)[off] = f2bf(vv);
                }
    }
}

__global__ __launch_bounds__(256, 2) void gemm_qkv(
    const unsigned short* __restrict__ qa, const unsigned short* __restrict__ ka,
    const unsigned short* __restrict__ va,
    const unsigned short* __restrict__ wq, const unsigned short* __restrict__ wk,
    const unsigned short* __restrict__ wv,
    const unsigned short* __restrict__ bq, const unsigned short* __restrict__ bk,
    const unsigned short* __restrict__ bv,
    unsigned short* __restrict__ oq, unsigned short* __restrict__ ok,
    unsigned short* __restrict__ ovT)
{
    if (blockIdx.z == 0)      gemm_core(qa, wq, bq, oq, 0);
    else if (blockIdx.z == 1) gemm_core(ka, wk, bk, ok, 0);
    else                      gemm_core(va, wv, bv, ovT, 2);   // V -> [bh][d][s]
}

__global__ __launch_bounds__(256, 2) void gemm_out(
    const unsigned short* __restrict__ A, const unsigned short* __restrict__ W,
    const unsigned short* __restrict__ B, void* __restrict__ C,
    const unsigned int* __restrict__ flagp)
{
    gemm_core(A, W, B, C, (int)*flagp);
}

// ---- MFMA flash attention v8 (unchanged from round 5, 57.1 us verified) ----
__global__ __launch_bounds__(256) void attn_mfma6(
    const unsigned short* __restrict__ Q,    // pre-scaled (log2 domain)
    const unsigned short* __restrict__ K,
    const unsigned short* __restrict__ VT,   // [bh][64][2048]
    unsigned short* __restrict__ CTX)
{
    __shared__ unsigned short Kl[3][64 * 64];     // 24 KB  [key][d] swizzled
    __shared__ unsigned short Vl[3][64 * 64];     // 24 KB  [d][key] swizzled
    __shared__ unsigned short Pl[4][2][16 * PPITCH];  // 18.4 KB

    const int tid  = threadIdx.x;
    const int w    = tid >> 6;
    const int lane = tid & 63;
    const int lo   = lane & 15;
    const int quad = lane >> 4;
    const int bh = blockIdx.y;
    const int b  = bh >> 4;
    const int h  = bh & 15;
    const int q0 = blockIdx.x * 128 + w * 32;

    bf16x8 aq[2][2];
    #pragma unroll
    for (int f = 0; f < 2; ++f)
        #pragma unroll
        for (int c = 0; c < 2; ++c)
            aq[f][c] = *(const bf16x8*)(Q + (size_t)(b * SEQ + q0 + f * 16 + lo) * DM
                                        + h * 64 + c * 32 + quad * 8);

    f32x4 o[2][4];
    #pragma unroll
    for (int f = 0; f < 2; ++f)
        #pragma unroll
        for (int dt = 0; dt < 4; ++dt) o[f][dt] = (f32x4){0.f, 0.f, 0.f, 0.f};
    f32x4 lacc[2];
    lacc[0] = (f32x4){0.f, 0.f, 0.f, 0.f};
    lacc[1] = (f32x4){0.f, 0.f, 0.f, 0.f};

    const short one_s = (short)0x3F80;   // bf16 1.0
    const bf16x8 ones = {one_s, one_s, one_s, one_s, one_s, one_s, one_s, one_s};

    const int r8  = lane >> 3;
    const int csw = ((lane ^ r8) & 7) * 8;
    const int swz = lo & 7;
    const unsigned short* Kg = K + (size_t)b * SEQ * DM + h * 64;
    const unsigned short* Vg = VT + (size_t)bh * 64 * 2048;

    // per-wave stage of key-tile jt into buffer bb: 4 gll16 (2 K + 2 V)
    #define STAGE(jt, bb) do {                                              \
        const int _jn = (jt) * 64;                                          \
        _Pragma("unroll")                                                   \
        for (int _j = 0; _j < 2; ++_j) {                                    \
            gll16(Kg + (size_t)(_jn + w * 16 + _j * 8 + r8) * DM + csw,     \
                  &Kl[bb][(w * 16 + _j * 8) * 64]);                         \
            gll16(Vg + (size_t)(w * 16 + _j * 8 + r8) * 2048 + _jn + csw,   \
                  &Vl[bb][(w * 16 + _j * 8) * 64]);                         \
        }                                                                   \
    } while (0)

    // prologue: stage tiles 0 and 1; wait for tile 0 only (vmcnt(4))
    STAGE(0, 0);
    STAGE(1, 1);
    asm volatile("s_waitcnt vmcnt(4)" ::: "memory");
    __builtin_amdgcn_s_barrier();
    __builtin_amdgcn_sched_barrier(0);

    const int NT = SEQ / 64;
    int cur = 0;
    for (int t = 0; t < NT; ++t) {
        // issue tile t+2's staging FIRST — two tiles of compute to hide under
        if (t + 2 < NT) {
            const int nb = (cur + 2 >= 3) ? cur - 1 : cur + 2;
            STAGE(t + 2, nb);
        }

        const unsigned short* Kc = Kl[cur];
        const unsigned short* Vc = Vl[cur];

        // S^T: rows = keys, cols = queries (already log2-scaled)
        f32x4 st[4][2];
        __builtin_amdgcn_s_setprio(1);
        #pragma unroll
        for (int kt = 0; kt < 4; ++kt) {
            bf16x8 ak0 = *(const bf16x8*)&Kc[(kt * 16 + lo) * 64 + ((quad ^ swz) * 8)];
            bf16x8 ak1 = *(const bf16x8*)&Kc[(kt * 16 + lo) * 64 + (((4 + quad) ^ swz) * 8)];
            #pragma unroll
            for (int f = 0; f < 2; ++f) {
                f32x4 c = (f32x4){0.f, 0.f, 0.f, 0.f};
                c = __builtin_amdgcn_mfma_f32_16x16x32_bf16(ak0, aq[f][0], c, 0, 0, 0);
                c = __builtin_amdgcn_mfma_f32_16x16x32_bf16(ak1, aq[f][1], c, 0, 0, 0);
                st[kt][f] = c;
            }
        }
        __builtin_amdgcn_s_setprio(0);

        // p = exp2(s); packed trunc P^T round-trip
        #pragma unroll
        for (int f = 0; f < 2; ++f)
            #pragma unroll
            for (int kt = 0; kt < 4; ++kt) {
                float p0 = __ocml_native_exp2_f32(st[kt][f][0]);
                float p1 = __ocml_native_exp2_f32(st[kt][f][1]);
                float p2 = __ocml_native_exp2_f32(st[kt][f][2]);
                float p3 = __ocml_native_exp2_f32(st[kt][f][3]);
                uint2 pv;
                pv.x = pk_trunc(p0, p1);
                pv.y = pk_trunc(p2, p3);
                *(uint2*)&Pl[w][f][lo * PPITCH + kt * 16 + quad * 4] = pv;
            }
        // same-wave write->read ordering via lgkmcnt
        bf16x8 ap[2][2];
        #pragma unroll
        for (int f = 0; f < 2; ++f)
            #pragma unroll
            for (int c = 0; c < 2; ++c)
                ap[f][c] = *(const bf16x8*)&Pl[w][f][lo * PPITCH + c * 32 + quad * 8];

        __builtin_amdgcn_s_setprio(1);
        // lsum via ones-MFMA: C[q][*] = sum_k P[q,k], rows match O layout
        #pragma unroll
        for (int f = 0; f < 2; ++f) {
            lacc[f] = __builtin_amdgcn_mfma_f32_16x16x32_bf16(ap[f][0], ones, lacc[f], 0, 0, 0);
            lacc[f] = __builtin_amdgcn_mfma_f32_16x16x32_bf16(ap[f][1], ones, lacc[f], 0, 0, 0);
        }

        #pragma unroll
        for (int dt = 0; dt < 4; ++dt) {
            bf16x8 bv0 = *(const bf16x8*)&Vc[(dt * 16 + lo) * 64 + ((quad ^ swz) * 8)];
            bf16x8 bv1 = *(const bf16x8*)&Vc[(dt * 16 + lo) * 64 + (((4 + quad) ^ swz) * 8)];
            #pragma unroll
            for (int f = 0; f < 2; ++f) {
                o[f][dt] = __builtin_amdgcn_mfma_f32_16x16x32_bf16(ap[f][0], bv0, o[f][dt], 0, 0, 0);
                o[f][dt] = __builtin_amdgcn_mfma_f32_16x16x32_bf16(ap[f][1], bv1, o[f][dt], 0, 0, 0);
            }
        }
        __builtin_amdgcn_s_setprio(0);

        // end of tile: t+1's 4 oldest loads must retire; t+2's 4 stay in
        // flight (counted vmcnt — never 0 in steady state). Tail drains.
        if (t + 2 < NT) {
            asm volatile("s_waitcnt vmcnt(4)" ::: "memory");
        } else {
            asm volatile("s_waitcnt vmcnt(0)" ::: "memory");
        }
        __builtin_amdgcn_s_barrier();
        __builtin_amdgcn_sched_barrier(0);

        cur = (cur == 2) ? 0 : cur + 1;
    }
    #undef STAGE

    // epilogue: l for row q=quad*4+r is lacc[f][r] in-lane — no shuffles
    #pragma unroll
    for (int f = 0; f < 2; ++f)
        #pragma unroll
        for (int r = 0; r < 4; ++r) {
            const float inv = 1.0f / lacc[f][r];
            const size_t base = (size_t)(b * SEQ + q0 + f * 16 + quad * 4 + r) * DM
                                + h * 64 + lo;
            #pragma unroll
            for (int dt = 0; dt < 4; ++dt)
                CTX[base + dt * 16] = f2bf(o[f][dt][r] * inv);
        }
}

extern "C" void kernel_launch(void* const* d_in, const int* in_sizes, int n_in,
                              void* d_out, int out_size, void* d_ws, size_t ws_size,
                              hipStream_t stream) {
    const size_t E4 = 4194304, E1 = 1048576;
    unsigned short* qb  = (unsigned short*)d_ws;
    unsigned short* kb  = qb  + E4;
    unsigned short* vb  = kb  + E4;
    unsigned short* wqb = vb  + E4;
    unsigned short* wkb = wqb + E1;
    unsigned short* wvb = wkb + E1;
    unsigned short* wob = wvb + E1;
    unsigned short* bqb = wob + E1;
    unsigned short* bkb = bqb + 1024;
    unsigned short* bvb = bkb + 1024;
    unsigned short* bob = bvb + 1024;
    unsigned short* wsQ = bob + 1024;
    unsigned short* wsK = wsQ + E4;
    unsigned short* wsVt = wsK + E4;   // V projection, [bh][64][2048]
    unsigned int*  flag = (unsigned int*)(wsVt + E4);
    unsigned short* wsC = qb;   // alias: qb dead after the QKV GEMM dispatch

    detect_dtype<<<1, 64, 0, stream>>>((const unsigned short*)d_in[0], flag);

    CvtArgs ca;
    ca.src[0] = d_in[0];  ca.dst[0] = qb;
    ca.src[1] = d_in[1];  ca.dst[1] = kb;
    ca.src[2] = d_in[2];  ca.dst[2] = vb;
    ca.src[3] = d_in[3];  ca.dst[3] = wqb;   // scaled 0.125*log2e
    ca.src[4] = d_in[5];  ca.dst[4] = wkb;
    ca.src[5] = d_in[7];  ca.dst[5] = wvb;
    ca.src[6] = d_in[9];  ca.dst[6] = wob;
    ca.src[7] = d_in[4];  ca.dst[7] = bqb;   // scaled 0.125*log2e
    ca.src[8] = d_in[6];  ca.dst[8] = bkb;
    ca.src[9] = d_in[8];  ca.dst[9] = bvb;
    ca.src[10] = d_in[10]; ca.dst[10] = bob;
    convert_all<<<(CVT_TOTAL / 8 + 255) / 256, 256, 0, stream>>>(ca, flag);

    dim3 gq(DM / 128, MROWS / 128, 3);   // (8, 32, 3) = 768 blocks
    gemm_qkv<<<gq, 256, 0, stream>>>(qb, kb, vb, wqb, wkb, wvb,
                                     bqb, bkb, bvb, wsQ, wsK, wsVt);

    dim3 ga(SEQ / 128, BATCH * NH);      // (16, 32)
    attn_mfma6<<<ga, 256, 0, stream>>>(wsQ, wsK, wsVt, wsC);

    dim3 go(DM / 128, MROWS / 128);      // (8, 32) = 256 blocks
    gemm_out<<<go, 256, 0, stream>>>(wsC, wob, bob, d_out, flag);
}